// Round 9
// baseline (12.364 us; speedup 1.0000x reference)
//
#include <hip/hip_runtime.h>
#include <hip/hip_bf16.h>

#define N_ENT 40943
#define DIM   128
#define NB    32
#define QPAD  136   // LDS row stride in bf16 elems (128+8): +4-bank shift/row, 16B aligned

typedef __attribute__((ext_vector_type(8))) short bfrag_t;
typedef __attribute__((ext_vector_type(4))) float f32x4_t;

__device__ inline short bf16_bits(float f) {
    __hip_bfloat16 h = __float2bfloat16(f);
    return *reinterpret_cast<short*>(&h);
}

// Single fused kernel. score[b,e] = ||q_b||^2 + ||t_e||^2 - 2 q_b . t_e
// t-row loads are issued BEFORE the prep phase so HBM latency hides under
// the q-gather + barrier (source-level hoist; compiler won't cross s_barrier).
__global__ __launch_bounds__(256) void transe_fused(
    const int* __restrict__ heads,
    const int* __restrict__ rels,
    const float* __restrict__ ent_w,
    const float* __restrict__ rel_w,
    float* __restrict__ out)
{
    __shared__ unsigned short qbf[NB][QPAD];  // q rows as bf16
    __shared__ float qn[NB];                  // ||q_b||^2

    const int tid  = threadIdx.x;
    const int lane = tid & 63;
    const int wid  = tid >> 6;
    const int e0   = (blockIdx.x * 4 + wid) * 16;

    const int er   = lane & 15;          // entity-in-tile == q row-in-tile
    const int kg   = lane >> 4;          // k-group 0..3 (8 contiguous k each)
    const int erow = e0 + er;
    const int eld  = erow < N_ENT ? erow : N_ENT - 1;   // clamp loads, mask stores

    // ---- issue t-row loads first (in flight during prep + barrier) ----
    const float* tp = ent_w + (size_t)eld * DIM + 8 * kg;
    f32x4_t tr0[4], tr1[4];
    #pragma unroll
    for (int kt = 0; kt < 4; ++kt) {
        tr0[kt] = *(const f32x4_t*)(tp + 32 * kt);
        tr1[kt] = *(const f32x4_t*)(tp + 32 * kt + 4);
    }

    // ---- prep: thread -> (batch b = tid>>3, 16-float chunk c = (tid&7)*16) ----
    {
        const int b = tid >> 3;
        const int c = (tid & 7) * 16;
        const int h = heads[b];
        const int r = rels[b];
        const float4* eh = (const float4*)(ent_w + (size_t)h * DIM + c);
        const float4* rr = (const float4*)(rel_w + (size_t)r * DIM + c);
        float part = 0.f;
        #pragma unroll
        for (int k = 0; k < 4; ++k) {
            float4 a = eh[k], bb = rr[k];
            float v0 = a.x + bb.x, v1 = a.y + bb.y, v2 = a.z + bb.z, v3 = a.w + bb.w;
            part = fmaf(v0, v0, fmaf(v1, v1, fmaf(v2, v2, fmaf(v3, v3, part))));
            short4 s;
            s.x = bf16_bits(v0); s.y = bf16_bits(v1);
            s.z = bf16_bits(v2); s.w = bf16_bits(v3);
            *(short4*)(&qbf[b][c + 4 * k]) = s;
        }
        part += __shfl_down(part, 4);
        part += __shfl_down(part, 2);
        part += __shfl_down(part, 1);
        if ((tid & 7) == 0) qn[b] = part;
    }
    __syncthreads();

    // ---- A fragments (q, bf16) from LDS: rows {er, er+16} ----
    bfrag_t a0[4], a1[4];
    #pragma unroll
    for (int kt = 0; kt < 4; ++kt) {
        a0[kt] = *(const bfrag_t*)(&qbf[er][8 * kg + 32 * kt]);
        a1[kt] = *(const bfrag_t*)(&qbf[er + 16][8 * kg + 32 * kt]);
    }

    // ---- convert staged t-rows, fold ||t||^2, MFMA ----
    f32x4_t acc0 = {0.f, 0.f, 0.f, 0.f};
    f32x4_t acc1 = {0.f, 0.f, 0.f, 0.f};
    float tn = 0.f;
    #pragma unroll
    for (int kt = 0; kt < 4; ++kt) {
        bfrag_t bf;
        #pragma unroll
        for (int j = 0; j < 4; ++j) {
            tn = fmaf(tr0[kt][j], tr0[kt][j], tn);
            tn = fmaf(tr1[kt][j], tr1[kt][j], tn);
            bf[j]     = bf16_bits(tr0[kt][j]);
            bf[j + 4] = bf16_bits(tr1[kt][j]);
        }
        acc0 = __builtin_amdgcn_mfma_f32_16x16x32_bf16(a0[kt], bf, acc0, 0, 0, 0);
        acc1 = __builtin_amdgcn_mfma_f32_16x16x32_bf16(a1[kt], bf, acc1, 0, 0, 0);
    }
    // lanes {er, er+16, er+32, er+48} hold complementary k-ranges of the same t-row
    tn += __shfl_xor(tn, 16);
    tn += __shfl_xor(tn, 32);

    if (erow < N_ENT) {
        #pragma unroll
        for (int r = 0; r < 4; ++r) {
            const int b0 = 4 * kg + r;   // C/D: row = 4*(lane>>4)+reg, col = lane&15
            out[(size_t)b0        * N_ENT + erow] = qn[b0]      + tn - 2.f * acc0[r];
            out[(size_t)(b0 + 16) * N_ENT + erow] = qn[b0 + 16] + tn - 2.f * acc1[r];
        }
    }
}

extern "C" void kernel_launch(void* const* d_in, const int* in_sizes, int n_in,
                              void* d_out, int out_size, void* d_ws, size_t ws_size,
                              hipStream_t stream) {
    const int*   heads = (const int*)d_in[0];
    const int*   rels  = (const int*)d_in[1];
    const float* ent_w = (const float*)d_in[2];
    const float* rel_w = (const float*)d_in[3];
    float* out = (float*)d_out;

    const int grid = (N_ENT + 63) / 64;   // 4 waves/block, 16 entities/wave -> 640 blocks
    transe_fused<<<grid, 256, 0, stream>>>(heads, rels, ent_w, rel_w, out);
}